// Round 3
// baseline (60203.070 us; speedup 1.0000x reference)
//
#include <hip/hip_runtime.h>
#include <stdint.h>
#include <math.h>

#define Bn 32768
#define Ln 7
#define Tn 6
#define En 256
#define Hn 256
#define Rr 8
#define NEGF (-1000000000.0f)

// ---------------------------------------------------------------------------
// ws layout (floats):
//   [0, 7*65536)            : 7 transposed weight matrices WT[m][e][h]
//                             order: Wh, Wv, Wsh, Wsv, Wedge, Win, Wctx
//   [458752, 458752+B*7)    : att[b][l]
//   [688128, 688142)        : S[7], logS[7]
// Total ~2.75 MB — no large global intermediates (edges live in LDS).
// ---------------------------------------------------------------------------

__device__ __forceinline__ uint32_t rotl32(uint32_t x, int d) {
  return (x << d) | (x >> (32 - d));
}

// JAX threefry2x32, 20 rounds (matches jax/_src/prng.py)
__device__ __forceinline__ void threefry2x32(uint32_t k0, uint32_t k1,
                                             uint32_t x0, uint32_t x1,
                                             uint32_t& o0, uint32_t& o1) {
  uint32_t k2 = k0 ^ k1 ^ 0x1BD11BDAu;
  x0 += k0; x1 += k1;
  x0 += x1; x1 = rotl32(x1, 13); x1 ^= x0;
  x0 += x1; x1 = rotl32(x1, 15); x1 ^= x0;
  x0 += x1; x1 = rotl32(x1, 26); x1 ^= x0;
  x0 += x1; x1 = rotl32(x1,  6); x1 ^= x0;
  x0 += k1; x1 += k2 + 1u;
  x0 += x1; x1 = rotl32(x1, 17); x1 ^= x0;
  x0 += x1; x1 = rotl32(x1, 29); x1 ^= x0;
  x0 += x1; x1 = rotl32(x1, 16); x1 ^= x0;
  x0 += x1; x1 = rotl32(x1, 24); x1 ^= x0;
  x0 += k2; x1 += k0 + 2u;
  x0 += x1; x1 = rotl32(x1, 13); x1 ^= x0;
  x0 += x1; x1 = rotl32(x1, 15); x1 ^= x0;
  x0 += x1; x1 = rotl32(x1, 26); x1 ^= x0;
  x0 += x1; x1 = rotl32(x1,  6); x1 ^= x0;
  x0 += k0; x1 += k1 + 3u;
  x0 += x1; x1 = rotl32(x1, 17); x1 ^= x0;
  x0 += x1; x1 = rotl32(x1, 29); x1 ^= x0;
  x0 += x1; x1 = rotl32(x1, 16); x1 ^= x0;
  x0 += x1; x1 = rotl32(x1, 24); x1 ^= x0;
  x0 += k1; x1 += k2 + 4u;
  x0 += x1; x1 = rotl32(x1, 13); x1 ^= x0;
  x0 += x1; x1 = rotl32(x1, 15); x1 ^= x0;
  x0 += x1; x1 = rotl32(x1, 26); x1 ^= x0;
  x0 += x1; x1 = rotl32(x1,  6); x1 ^= x0;
  x0 += k2; x1 += k0 + 5u;
  o0 = x0; o1 = x1;
}

// ---------------------------------------------------------------------------
// Transpose the 7 weight matrices (256x256 each) into ws.
// ---------------------------------------------------------------------------
__global__ __launch_bounds__(256) void k_transpose(
    const float* __restrict__ w0, const float* __restrict__ w1,
    const float* __restrict__ w2, const float* __restrict__ w3,
    const float* __restrict__ w4, const float* __restrict__ w5,
    const float* __restrict__ w6, float* __restrict__ dst) {
  const float* src;
  switch (blockIdx.y) {
    case 0: src = w0; break;
    case 1: src = w1; break;
    case 2: src = w2; break;
    case 3: src = w3; break;
    case 4: src = w4; break;
    case 5: src = w5; break;
    default: src = w6; break;
  }
  int e = blockIdx.x;       // grid.x = 256
  int h = threadIdx.x;      // 256 threads
  dst[(size_t)blockIdx.y * 65536 + e * 256 + h] = src[h * 256 + e];
}

// ---------------------------------------------------------------------------
// Main fused kernel: one WG (256 threads, thread = h channel) per 8 rows.
//
// ANTI-SPILL DESIGN (the two previous rounds died on LICM hoisting of
// loop-invariant uniform values into VGPRs):
//   * gather triples are read from LDS through a VOLATILE pointer inside
//     the e0 loop -> cannot be hoisted; only 2 transient scalars live.
//   * edges[5][8] are staged in LDS (40KB), not in a reg array concurrent
//     with other state and not in global memory.
//   * ctx loops l OUTERMOST: only cx[8] + 8 derived pointers live
//     (hoisting 8 uniform pointers is harmless; 56 was the bomb).
//   * every register array statically indexed; every e0 loop unroll 1.
// Max live VGPR set ~85-95 at any point.
//
// LDS: edges 40KB + qt 8KB + pack 320B + red 128B = 48.5KB -> 3 blocks/CU.
// ---------------------------------------------------------------------------
__global__ __launch_bounds__(256, 3) void k_main(
    const float* __restrict__ enc, const int* __restrict__ xes,
    const int* __restrict__ maskp, const float* __restrict__ wt,
    const float* __restrict__ b_in, const float* __restrict__ b_ctx,
    const float* __restrict__ V, float* __restrict__ att_out) {
  const int t = threadIdx.x;
  const int b0 = blockIdx.x * Rr;

  const float* WhT   = wt;
  const float* WvT   = wt + 65536;
  const float* WshT  = wt + 2 * 65536;
  const float* WsvT  = wt + 3 * 65536;
  const float* WeT   = wt + 4 * 65536;
  const float* WinT  = wt + 5 * 65536;
  const float* WctxT = wt + 6 * 65536;

  __shared__ int   s_pack[5 * Rr * 2];     // {offh|cond, offv} per (tt,r)
  __shared__ float s_edges[5 * Rr * 256];  // 40KB: edge_tt[r][t]
  __shared__ float s_qt[Rr * 256];         // 8KB: qt[r][t]
  __shared__ float s_red[4 * Rr];

  if (t < 5 * Rr) {
    int tt = t >> 3, r = t & 7;
    int base = ((b0 + r) * Tn + tt) * 3;
    int hi = xes[base], vi = xes[base + 1], tc = xes[base + 2];
    int oh = ((b0 + r) * Ln + hi) * En;   // multiple of 256 -> bit0 free
    int ov = ((b0 + r) * Ln + vi) * En;
    s_pack[t * 2]     = oh | ((tc == 0) ? 1 : 0);
    s_pack[t * 2 + 1] = ov;
  }
  __syncthreads();

  // ---- P1: edges for tt=0..4, acc[5][8], weights loaded once per e0 ----
  float acc[5][Rr];
#pragma unroll
  for (int i = 0; i < 5; i++)
#pragma unroll
    for (int r = 0; r < Rr; r++) acc[i][r] = 0.f;

  volatile const int* vp = s_pack;   // volatile: LICM cannot hoist these

#pragma unroll 1
  for (int e0 = 0; e0 < En; e0 += 8) {
    float wh[8], wv[8], wsh[8], wsv[8];
#pragma unroll
    for (int j = 0; j < 8; j++) {
      int o = (e0 + j) * 256 + t;
      wh[j] = WhT[o]; wv[j] = WvT[o]; wsh[j] = WshT[o]; wsv[j] = WsvT[o];
    }
#pragma unroll
    for (int tt = 0; tt < 5; tt++) {
#pragma unroll
      for (int r = 0; r < Rr; r++) {
        int w0 = __builtin_amdgcn_readfirstlane(vp[(tt * Rr + r) * 2]);
        int w1 = __builtin_amdgcn_readfirstlane(vp[(tt * Rr + r) * 2 + 1]);
        int cond = w0 & 1;
        const float* __restrict__ ph = enc + (w0 - cond) + e0;
        const float* __restrict__ pv = enc + w1 + e0;
        float a = acc[tt][r];
        if (cond) {
#pragma unroll
          for (int j = 0; j < 8; j++) a += wh[j] * ph[j] + wv[j] * pv[j];
        } else {
#pragma unroll
          for (int j = 0; j < 8; j++) a += wsh[j] * ph[j] + wsv[j] * pv[j];
        }
        acc[tt][r] = a;
      }
    }
  }

  // stage edges to LDS (lane-consecutive -> conflict-free)
#pragma unroll
  for (int tt = 0; tt < 5; tt++)
#pragma unroll
    for (int r = 0; r < Rr; r++)
      s_edges[(tt * Rr + r) * 256 + t] = acc[tt][r];
  __syncthreads();

  // ---- P2: m[tt][r] = (edge_tt @ We^T)[r][t], single WeT pass ----------
  float m[5][Rr];
#pragma unroll
  for (int i = 0; i < 5; i++)
#pragma unroll
    for (int r = 0; r < Rr; r++) m[i][r] = 0.f;

#pragma unroll 1
  for (int e0 = 0; e0 < En; e0 += 8) {
    float w8[8];
#pragma unroll
    for (int j = 0; j < 8; j++) w8[j] = WeT[(e0 + j) * 256 + t];
#pragma unroll
    for (int tt = 0; tt < 5; tt++) {
#pragma unroll
      for (int r = 0; r < Rr; r++) {
        const float* xb = &s_edges[(tt * Rr + r) * 256 + e0];  // uniform
        float4 xa = *(const float4*)(xb);
        float4 xc = *(const float4*)(xb + 4);
        float s = m[tt][r];
        s += w8[0] * xa.x; s += w8[1] * xa.y;
        s += w8[2] * xa.z; s += w8[3] * xa.w;
        s += w8[4] * xc.x; s += w8[5] * xc.y;
        s += w8[6] * xc.z; s += w8[7] * xc.w;
        m[tt][r] = s;
      }
    }
  }

  // ---- P3: st = max(0, max_tt m); qt = relu(edge4 + st) ----------------
#pragma unroll
  for (int r = 0; r < Rr; r++) {
    float s = fmaxf(fmaxf(fmaxf(m[0][r], m[1][r]), fmaxf(m[2][r], m[3][r])),
                    m[4][r]);
    s = fmaxf(s, 0.f);
    float e4 = s_edges[(4 * Rr + r) * 256 + t];   // per-lane, own t
    s_qt[r * 256 + t] = fmaxf(e4 + s, 0.f);
  }
  __syncthreads();

  // ---- P4: inp[r] = qt[r] @ Win^T + b_in (at own t) --------------------
  float inp[Rr];
#pragma unroll
  for (int r = 0; r < Rr; r++) inp[r] = 0.f;
#pragma unroll 1
  for (int e0 = 0; e0 < En; e0 += 8) {
    float w8[8];
#pragma unroll
    for (int j = 0; j < 8; j++) w8[j] = WinT[(e0 + j) * 256 + t];
#pragma unroll
    for (int r = 0; r < Rr; r++) {
      const float* xb = &s_qt[r * 256 + e0];      // uniform
      float4 xa = *(const float4*)(xb);
      float4 xc = *(const float4*)(xb + 4);
      float s = inp[r];
      s += w8[0] * xa.x; s += w8[1] * xa.y;
      s += w8[2] * xa.z; s += w8[3] * xa.w;
      s += w8[4] * xc.x; s += w8[5] * xc.y;
      s += w8[6] * xc.z; s += w8[7] * xc.w;
      inp[r] = s;
    }
  }
  {
    float bi = b_in[t];
#pragma unroll
    for (int r = 0; r < Rr; r++) inp[r] += bi;
  }

  // ---- P5+P6: per l: cx[8] = enc[b,l,:]@Wctx^T; fused att reduce -------
  // l OUTERMOST: only cx[8] + 8 derived pointers live (no 56-pointer
  // hoist). Wctx re-read per l (256KB, L2-resident) is the safety price.
  const float Vt = V[t];
  const float bc = b_ctx[t];
  const int lane = t & 63, wid = t >> 6;

#pragma unroll 1
  for (int l = 0; l < Ln; l++) {
    float cx[Rr];
#pragma unroll
    for (int r = 0; r < Rr; r++) cx[r] = 0.f;

#pragma unroll 1
    for (int e0 = 0; e0 < En; e0 += 8) {
      float w8[8];
#pragma unroll
      for (int j = 0; j < 8; j++) w8[j] = WctxT[(e0 + j) * 256 + t];
#pragma unroll
      for (int r = 0; r < Rr; r++) {
        const float* __restrict__ px = enc + ((b0 + r) * Ln + l) * En + e0;
        float c = cx[r];
#pragma unroll
        for (int j = 0; j < 8; j++) c += w8[j] * px[j];
        cx[r] = c;
      }
    }

    float v8[Rr];
#pragma unroll
    for (int r = 0; r < Rr; r++) v8[r] = Vt * tanhf(inp[r] + bc + cx[r]);
#pragma unroll
    for (int off = 32; off > 0; off >>= 1) {
#pragma unroll
      for (int r = 0; r < Rr; r++) v8[r] += __shfl_down(v8[r], off, 64);
    }
    if (lane == 0) {
#pragma unroll
      for (int r = 0; r < Rr; r++) s_red[wid * Rr + r] = v8[r];
    }
    __syncthreads();
    if (t < Rr) {
      float a = s_red[t] + s_red[Rr + t] + s_red[2 * Rr + t] +
                s_red[3 * Rr + t];
      int b = b0 + t;
      if (!maskp[b * Ln + l]) a = NEGF;
      a = 10.f * tanhf(a);
      att_out[b * Ln + l] = a;
    }
    __syncthreads();
  }
}

// ---------------------------------------------------------------------------
// Column sums for softmax over axis 0 (fp64 accumulation).
// ---------------------------------------------------------------------------
__global__ __launch_bounds__(256) void k_colsum(const float* __restrict__ att,
                                                float* __restrict__ sbuf) {
  int l = blockIdx.x;     // 0..6
  int t = threadIdx.x;
  double s = 0.0;
  for (int b = t; b < Bn; b += 256) s += exp((double)att[b * Ln + l]);
  __shared__ double sd[256];
  sd[t] = s;
  __syncthreads();
  for (int k = 128; k > 0; k >>= 1) {
    if (t < k) sd[t] += sd[t + k];
    __syncthreads();
  }
  if (t == 0) {
    sbuf[l] = (float)sd[0];
    sbuf[7 + l] = (float)log(sd[0]);
  }
}

// ---------------------------------------------------------------------------
// Gumbel-argmax sampling (threefry, partitionable bit-stream) + outputs.
// out = [idx(B) | p(B) | new_mask(B*7)] as float32.
// ---------------------------------------------------------------------------
__global__ __launch_bounds__(256) void k_sample(const float* __restrict__ att,
                                                const float* __restrict__ sbuf,
                                                const int* __restrict__ maskp,
                                                float* __restrict__ out) {
  int b = blockIdx.x * 256 + threadIdx.x;
  if (b >= Bn) return;
  float best = -3.0e38f;
  int bi = 0;
#pragma unroll
  for (int l = 0; l < Ln; l++) {
    uint32_t n = (uint32_t)(b * Ln + l);
    uint32_t o0, o1;
    threefry2x32(0u, 42u, 0u, n, o0, o1);   // counts64 = n -> (hi=0, lo=n)
    uint32_t bits = o0 ^ o1;                 // partitionable 32-bit fold
    uint32_t fb = (bits >> 9) | 0x3f800000u;
    float f = __uint_as_float(fb) - 1.0f;
    float u = fmaxf(f, 1.1754943508222875e-38f);
    float g = -logf(-logf(u));
    float y = att[b * Ln + l] - sbuf[7 + l] + g;
    if (y > best) { best = y; bi = l; }
  }
  out[b] = (float)bi;
  out[Bn + b] = expf(att[b * Ln + bi] - sbuf[7 + bi]);
#pragma unroll
  for (int l = 0; l < Ln; l++)
    out[2 * Bn + b * Ln + l] = (float)(maskp[b * Ln + l] - ((l == bi) ? 1 : 0));
}

// ---------------------------------------------------------------------------
extern "C" void kernel_launch(void* const* d_in, const int* in_sizes, int n_in,
                              void* d_out, int out_size, void* d_ws,
                              size_t ws_size, hipStream_t stream) {
  const float* enc   = (const float*)d_in[0];
  const int*   xes   = (const int*)d_in[1];
  const int*   maskp = (const int*)d_in[2];
  const float* W_h   = (const float*)d_in[3];
  const float* W_v   = (const float*)d_in[4];
  const float* Ws_h  = (const float*)d_in[5];
  const float* Ws_v  = (const float*)d_in[6];
  const float* W_e   = (const float*)d_in[7];
  const float* W_in  = (const float*)d_in[8];
  const float* b_in  = (const float*)d_in[9];
  const float* W_ctx = (const float*)d_in[10];
  const float* b_ctx = (const float*)d_in[11];
  const float* V     = (const float*)d_in[12];

  float* ws   = (float*)d_ws;
  float* wt   = ws;                   // 7*65536 floats
  float* att  = ws + 7 * 65536;       // B*7 floats
  float* sbuf = att + Bn * Ln;        // 14 floats

  dim3 gT(256, 7);
  k_transpose<<<gT, 256, 0, stream>>>(W_h, W_v, Ws_h, Ws_v, W_e, W_in, W_ctx, wt);
  k_main<<<Bn / Rr, 256, 0, stream>>>(enc, xes, maskp, wt, b_in, b_ctx, V, att);
  k_colsum<<<7, 256, 0, stream>>>(att, sbuf);
  k_sample<<<Bn / 256, 256, 0, stream>>>(att, sbuf, maskp, (float*)d_out);
}

// Round 4
// 21973.872 us; speedup vs baseline: 2.7398x; 2.7398x over previous
//
#include <hip/hip_runtime.h>
#include <stdint.h>
#include <math.h>

#define Bn 32768
#define Ln 7
#define Tn 6
#define En 256
#define Hn 256
#define Rr 8
#define NEGF (-1000000000.0f)

// ---------------------------------------------------------------------------
// ws layout (floats):
//   [0, 7*65536)            : 7 transposed weight matrices WT[m][e][h]
//                             order: Wh, Wv, Wsh, Wsv, Wedge, Win, Wctx
//   [458752, 458752+B*7)    : att[b][l]
//   [688128, 688142)        : S[7], logS[7]
// Total ~2.75 MB — no large global intermediates (edges live in LDS).
// ---------------------------------------------------------------------------

__device__ __forceinline__ uint32_t rotl32(uint32_t x, int d) {
  return (x << d) | (x >> (32 - d));
}

// JAX threefry2x32, 20 rounds (matches jax/_src/prng.py)
__device__ __forceinline__ void threefry2x32(uint32_t k0, uint32_t k1,
                                             uint32_t x0, uint32_t x1,
                                             uint32_t& o0, uint32_t& o1) {
  uint32_t k2 = k0 ^ k1 ^ 0x1BD11BDAu;
  x0 += k0; x1 += k1;
  x0 += x1; x1 = rotl32(x1, 13); x1 ^= x0;
  x0 += x1; x1 = rotl32(x1, 15); x1 ^= x0;
  x0 += x1; x1 = rotl32(x1, 26); x1 ^= x0;
  x0 += x1; x1 = rotl32(x1,  6); x1 ^= x0;
  x0 += k1; x1 += k2 + 1u;
  x0 += x1; x1 = rotl32(x1, 17); x1 ^= x0;
  x0 += x1; x1 = rotl32(x1, 29); x1 ^= x0;
  x0 += x1; x1 = rotl32(x1, 16); x1 ^= x0;
  x0 += x1; x1 = rotl32(x1, 24); x1 ^= x0;
  x0 += k2; x1 += k0 + 2u;
  x0 += x1; x1 = rotl32(x1, 13); x1 ^= x0;
  x0 += x1; x1 = rotl32(x1, 15); x1 ^= x0;
  x0 += x1; x1 = rotl32(x1, 26); x1 ^= x0;
  x0 += x1; x1 = rotl32(x1,  6); x1 ^= x0;
  x0 += k0; x1 += k1 + 3u;
  x0 += x1; x1 = rotl32(x1, 17); x1 ^= x0;
  x0 += x1; x1 = rotl32(x1, 29); x1 ^= x0;
  x0 += x1; x1 = rotl32(x1, 16); x1 ^= x0;
  x0 += x1; x1 = rotl32(x1, 24); x1 ^= x0;
  x0 += k1; x1 += k2 + 4u;
  x0 += x1; x1 = rotl32(x1, 13); x1 ^= x0;
  x0 += x1; x1 = rotl32(x1, 15); x1 ^= x0;
  x0 += x1; x1 = rotl32(x1, 26); x1 ^= x0;
  x0 += x1; x1 = rotl32(x1,  6); x1 ^= x0;
  x0 += k2; x1 += k0 + 5u;
  o0 = x0; o1 = x1;
}

// ---------------------------------------------------------------------------
// Transpose the 7 weight matrices (256x256 each) into ws.
// ---------------------------------------------------------------------------
__global__ __launch_bounds__(256) void k_transpose(
    const float* __restrict__ w0, const float* __restrict__ w1,
    const float* __restrict__ w2, const float* __restrict__ w3,
    const float* __restrict__ w4, const float* __restrict__ w5,
    const float* __restrict__ w6, float* __restrict__ dst) {
  const float* src;
  switch (blockIdx.y) {
    case 0: src = w0; break;
    case 1: src = w1; break;
    case 2: src = w2; break;
    case 3: src = w3; break;
    case 4: src = w4; break;
    case 5: src = w5; break;
    default: src = w6; break;
  }
  int e = blockIdx.x;       // grid.x = 256
  int h = threadIdx.x;      // 256 threads
  dst[(size_t)blockIdx.y * 65536 + e * 256 + h] = src[h * 256 + e];
}

// ---------------------------------------------------------------------------
// Main fused kernel: one WG (256 threads, thread = h channel) per 8 rows.
//
// KEY FIX vs rounds 1-3: __launch_bounds__(256, 1).
// Observed allocator pattern: with min-waves arg N it allocates 512/(2N)
// VGPRs (N=2 -> 128, N=3 -> 84) and SPILLS everything above that — the
// 65-93 GB/dispatch of scratch RMW traffic that dominated all three rounds.
// With N=1 the budget is 256 VGPRs; the structural live set (~110, up to
// ~170 with LICM-hoisted gather offsets) fits with zero spill. Low
// occupancy (2 waves/EU) is fine: 40 independent FMA accumulator chains
// per thread provide the ILP.
//
// LDS: edges 40KB + qt 8KB + pack 320B + red 128B = 48.5KB.
// ---------------------------------------------------------------------------
__global__ __launch_bounds__(256, 1) void k_main(
    const float* __restrict__ enc, const int* __restrict__ xes,
    const int* __restrict__ maskp, const float* __restrict__ wt,
    const float* __restrict__ b_in, const float* __restrict__ b_ctx,
    const float* __restrict__ V, float* __restrict__ att_out) {
  const int t = threadIdx.x;
  const int b0 = blockIdx.x * Rr;

  const float* WhT   = wt;
  const float* WvT   = wt + 65536;
  const float* WshT  = wt + 2 * 65536;
  const float* WsvT  = wt + 3 * 65536;
  const float* WeT   = wt + 4 * 65536;
  const float* WinT  = wt + 5 * 65536;
  const float* WctxT = wt + 6 * 65536;

  __shared__ int   s_pack[5 * Rr * 2];     // {offh|cond, offv} per (tt,r)
  __shared__ float s_edges[5 * Rr * 256];  // 40KB: edge_tt[r][t]
  __shared__ float s_qt[Rr * 256];         // 8KB: qt[r][t]
  __shared__ float s_red[4 * Rr];

  if (t < 5 * Rr) {
    int tt = t >> 3, r = t & 7;
    int base = ((b0 + r) * Tn + tt) * 3;
    int hi = xes[base], vi = xes[base + 1], tc = xes[base + 2];
    int oh = ((b0 + r) * Ln + hi) * En;   // multiple of 256 -> bit0 free
    int ov = ((b0 + r) * Ln + vi) * En;
    s_pack[t * 2]     = oh | ((tc == 0) ? 1 : 0);
    s_pack[t * 2 + 1] = ov;
  }
  __syncthreads();

  // ---- P1: edges for tt=0..4, acc[5][8], weights loaded once per e0 ----
  float acc[5][Rr];
#pragma unroll
  for (int i = 0; i < 5; i++)
#pragma unroll
    for (int r = 0; r < Rr; r++) acc[i][r] = 0.f;

#pragma unroll 1
  for (int e0 = 0; e0 < En; e0 += 8) {
    float wh[8], wv[8], wsh[8], wsv[8];
#pragma unroll
    for (int j = 0; j < 8; j++) {
      int o = (e0 + j) * 256 + t;
      wh[j] = WhT[o]; wv[j] = WvT[o]; wsh[j] = WshT[o]; wsv[j] = WsvT[o];
    }
#pragma unroll
    for (int tt = 0; tt < 5; tt++) {
#pragma unroll
      for (int r = 0; r < Rr; r++) {
        int w0 = __builtin_amdgcn_readfirstlane(s_pack[(tt * Rr + r) * 2]);
        int w1 = __builtin_amdgcn_readfirstlane(s_pack[(tt * Rr + r) * 2 + 1]);
        int cond = w0 & 1;
        const float* __restrict__ ph = enc + (w0 - cond) + e0;
        const float* __restrict__ pv = enc + w1 + e0;
        float a = acc[tt][r];
        if (cond) {
#pragma unroll
          for (int j = 0; j < 8; j++) a += wh[j] * ph[j] + wv[j] * pv[j];
        } else {
#pragma unroll
          for (int j = 0; j < 8; j++) a += wsh[j] * ph[j] + wsv[j] * pv[j];
        }
        acc[tt][r] = a;
      }
    }
  }

  // stage edges to LDS (lane-consecutive -> conflict-free)
#pragma unroll
  for (int tt = 0; tt < 5; tt++)
#pragma unroll
    for (int r = 0; r < Rr; r++)
      s_edges[(tt * Rr + r) * 256 + t] = acc[tt][r];
  __syncthreads();

  // ---- P2: m[tt][r] = (edge_tt @ We^T)[r][t], single WeT pass ----------
  float m[5][Rr];
#pragma unroll
  for (int i = 0; i < 5; i++)
#pragma unroll
    for (int r = 0; r < Rr; r++) m[i][r] = 0.f;

#pragma unroll 1
  for (int e0 = 0; e0 < En; e0 += 8) {
    float w8[8];
#pragma unroll
    for (int j = 0; j < 8; j++) w8[j] = WeT[(e0 + j) * 256 + t];
#pragma unroll
    for (int tt = 0; tt < 5; tt++) {
#pragma unroll
      for (int r = 0; r < Rr; r++) {
        const float* xb = &s_edges[(tt * Rr + r) * 256 + e0];  // uniform
        float4 xa = *(const float4*)(xb);
        float4 xc = *(const float4*)(xb + 4);
        float s = m[tt][r];
        s += w8[0] * xa.x; s += w8[1] * xa.y;
        s += w8[2] * xa.z; s += w8[3] * xa.w;
        s += w8[4] * xc.x; s += w8[5] * xc.y;
        s += w8[6] * xc.z; s += w8[7] * xc.w;
        m[tt][r] = s;
      }
    }
  }

  // ---- P3: st = max(0, max_tt m); qt = relu(edge4 + st) ----------------
#pragma unroll
  for (int r = 0; r < Rr; r++) {
    float s = fmaxf(fmaxf(fmaxf(m[0][r], m[1][r]), fmaxf(m[2][r], m[3][r])),
                    m[4][r]);
    s = fmaxf(s, 0.f);
    float e4 = s_edges[(4 * Rr + r) * 256 + t];   // per-lane, own t
    s_qt[r * 256 + t] = fmaxf(e4 + s, 0.f);
  }
  __syncthreads();

  // ---- P4: inp[r] = qt[r] @ Win^T + b_in (at own t) --------------------
  float inp[Rr];
#pragma unroll
  for (int r = 0; r < Rr; r++) inp[r] = 0.f;
#pragma unroll 1
  for (int e0 = 0; e0 < En; e0 += 8) {
    float w8[8];
#pragma unroll
    for (int j = 0; j < 8; j++) w8[j] = WinT[(e0 + j) * 256 + t];
#pragma unroll
    for (int r = 0; r < Rr; r++) {
      const float* xb = &s_qt[r * 256 + e0];      // uniform
      float4 xa = *(const float4*)(xb);
      float4 xc = *(const float4*)(xb + 4);
      float s = inp[r];
      s += w8[0] * xa.x; s += w8[1] * xa.y;
      s += w8[2] * xa.z; s += w8[3] * xa.w;
      s += w8[4] * xc.x; s += w8[5] * xc.y;
      s += w8[6] * xc.z; s += w8[7] * xc.w;
      inp[r] = s;
    }
  }
  {
    float bi = b_in[t];
#pragma unroll
    for (int r = 0; r < Rr; r++) inp[r] += bi;
  }

  // ---- P5+P6: per l: cx[8] = enc[b,l,:]@Wctx^T; fused att reduce -------
  // l OUTERMOST: only cx[8] + 8 derived pointers live per l iteration.
  // Wctx re-read per l (256KB, L2-resident).
  const float Vt = V[t];
  const float bc = b_ctx[t];
  const int lane = t & 63, wid = t >> 6;

#pragma unroll 1
  for (int l = 0; l < Ln; l++) {
    float cx[Rr];
#pragma unroll
    for (int r = 0; r < Rr; r++) cx[r] = 0.f;

#pragma unroll 1
    for (int e0 = 0; e0 < En; e0 += 8) {
      float w8[8];
#pragma unroll
      for (int j = 0; j < 8; j++) w8[j] = WctxT[(e0 + j) * 256 + t];
#pragma unroll
      for (int r = 0; r < Rr; r++) {
        const float* __restrict__ px = enc + ((b0 + r) * Ln + l) * En + e0;
        float c = cx[r];
#pragma unroll
        for (int j = 0; j < 8; j++) c += w8[j] * px[j];
        cx[r] = c;
      }
    }

    float v8[Rr];
#pragma unroll
    for (int r = 0; r < Rr; r++) v8[r] = Vt * tanhf(inp[r] + bc + cx[r]);
#pragma unroll
    for (int off = 32; off > 0; off >>= 1) {
#pragma unroll
      for (int r = 0; r < Rr; r++) v8[r] += __shfl_down(v8[r], off, 64);
    }
    if (lane == 0) {
#pragma unroll
      for (int r = 0; r < Rr; r++) s_red[wid * Rr + r] = v8[r];
    }
    __syncthreads();
    if (t < Rr) {
      float a = s_red[t] + s_red[Rr + t] + s_red[2 * Rr + t] +
                s_red[3 * Rr + t];
      int b = b0 + t;
      if (!maskp[b * Ln + l]) a = NEGF;
      a = 10.f * tanhf(a);
      att_out[b * Ln + l] = a;
    }
    __syncthreads();
  }
}

// ---------------------------------------------------------------------------
// Column sums for softmax over axis 0 (fp64 accumulation).
// ---------------------------------------------------------------------------
__global__ __launch_bounds__(256) void k_colsum(const float* __restrict__ att,
                                                float* __restrict__ sbuf) {
  int l = blockIdx.x;     // 0..6
  int t = threadIdx.x;
  double s = 0.0;
  for (int b = t; b < Bn; b += 256) s += exp((double)att[b * Ln + l]);
  __shared__ double sd[256];
  sd[t] = s;
  __syncthreads();
  for (int k = 128; k > 0; k >>= 1) {
    if (t < k) sd[t] += sd[t + k];
    __syncthreads();
  }
  if (t == 0) {
    sbuf[l] = (float)sd[0];
    sbuf[7 + l] = (float)log(sd[0]);
  }
}

// ---------------------------------------------------------------------------
// Gumbel-argmax sampling (threefry, partitionable bit-stream) + outputs.
// out = [idx(B) | p(B) | new_mask(B*7)] as float32.
// ---------------------------------------------------------------------------
__global__ __launch_bounds__(256) void k_sample(const float* __restrict__ att,
                                                const float* __restrict__ sbuf,
                                                const int* __restrict__ maskp,
                                                float* __restrict__ out) {
  int b = blockIdx.x * 256 + threadIdx.x;
  if (b >= Bn) return;
  float best = -3.0e38f;
  int bi = 0;
#pragma unroll
  for (int l = 0; l < Ln; l++) {
    uint32_t n = (uint32_t)(b * Ln + l);
    uint32_t o0, o1;
    threefry2x32(0u, 42u, 0u, n, o0, o1);   // counts64 = n -> (hi=0, lo=n)
    uint32_t bits = o0 ^ o1;                 // partitionable 32-bit fold
    uint32_t fb = (bits >> 9) | 0x3f800000u;
    float f = __uint_as_float(fb) - 1.0f;
    float u = fmaxf(f, 1.1754943508222875e-38f);
    float g = -logf(-logf(u));
    float y = att[b * Ln + l] - sbuf[7 + l] + g;
    if (y > best) { best = y; bi = l; }
  }
  out[b] = (float)bi;
  out[Bn + b] = expf(att[b * Ln + bi] - sbuf[7 + bi]);
#pragma unroll
  for (int l = 0; l < Ln; l++)
    out[2 * Bn + b * Ln + l] = (float)(maskp[b * Ln + l] - ((l == bi) ? 1 : 0));
}

// ---------------------------------------------------------------------------
extern "C" void kernel_launch(void* const* d_in, const int* in_sizes, int n_in,
                              void* d_out, int out_size, void* d_ws,
                              size_t ws_size, hipStream_t stream) {
  const float* enc   = (const float*)d_in[0];
  const int*   xes   = (const int*)d_in[1];
  const int*   maskp = (const int*)d_in[2];
  const float* W_h   = (const float*)d_in[3];
  const float* W_v   = (const float*)d_in[4];
  const float* Ws_h  = (const float*)d_in[5];
  const float* Ws_v  = (const float*)d_in[6];
  const float* W_e   = (const float*)d_in[7];
  const float* W_in  = (const float*)d_in[8];
  const float* b_in  = (const float*)d_in[9];
  const float* W_ctx = (const float*)d_in[10];
  const float* b_ctx = (const float*)d_in[11];
  const float* V     = (const float*)d_in[12];

  float* ws   = (float*)d_ws;
  float* wt   = ws;                   // 7*65536 floats
  float* att  = ws + 7 * 65536;       // B*7 floats
  float* sbuf = att + Bn * Ln;        // 14 floats

  dim3 gT(256, 7);
  k_transpose<<<gT, 256, 0, stream>>>(W_h, W_v, Ws_h, Ws_v, W_e, W_in, W_ctx, wt);
  k_main<<<Bn / Rr, 256, 0, stream>>>(enc, xes, maskp, wt, b_in, b_ctx, V, att);
  k_colsum<<<7, 256, 0, stream>>>(att, sbuf);
  k_sample<<<Bn / 256, 256, 0, stream>>>(att, sbuf, maskp, (float*)d_out);
}